// Round 1
// baseline (3244.019 us; speedup 1.0000x reference)
//
#include <hip/hip_runtime.h>
#include <hip/hip_bf16.h>

// Problem constants
#define Bn 4
#define Tn 2048
#define Cn 1024
#define Hn 16
#define Dn 64
// M = B*T = 8192, qkv N = 3072, K = 1024

// ---------------------------------------------------------------------------
// GEMM 1: X[8192,1024] @ W[1024,3072] + b, scatter into Q/K/V [B,H,T,D]
// tile 64x64, K-step 16, 256 threads, 4x4 micro-tile per thread.
// ---------------------------------------------------------------------------
__global__ __launch_bounds__(256) void qkv_gemm(
    const float* __restrict__ X, const float* __restrict__ W,
    const float* __restrict__ bias,
    float* __restrict__ Qb, float* __restrict__ Kb, float* __restrict__ Vb)
{
    const int m0 = blockIdx.y * 64;
    const int n0 = blockIdx.x * 64;
    const int t  = threadIdx.x;
    const int tx = t & 15, ty = t >> 4;

    __shared__ float As[16][68];  // [k][m], padded for float4 + banks
    __shared__ float Bs[16][68];  // [k][n]

    float acc[4][4] = {};

    const int amr = t >> 2,  akc = (t & 3) * 4;   // A: row amr, 4 k's at akc
    const int bkr = t >> 4,  bnc = (t & 15) * 4;  // B: k-row bkr, 4 n's at bnc

    for (int k0 = 0; k0 < 1024; k0 += 16) {
        float4 av = *(const float4*)&X[(size_t)(m0 + amr) * 1024 + k0 + akc];
        float4 bv = *(const float4*)&W[(size_t)(k0 + bkr) * 3072 + n0 + bnc];
        __syncthreads();  // previous iteration's reads done
        As[akc + 0][amr] = av.x;
        As[akc + 1][amr] = av.y;
        As[akc + 2][amr] = av.z;
        As[akc + 3][amr] = av.w;
        *(float4*)&Bs[bkr][bnc] = bv;
        __syncthreads();
        #pragma unroll
        for (int kk = 0; kk < 16; kk++) {
            float a0 = As[kk][ty * 4 + 0];
            float a1 = As[kk][ty * 4 + 1];
            float a2 = As[kk][ty * 4 + 2];
            float a3 = As[kk][ty * 4 + 3];
            float b0 = Bs[kk][tx * 4 + 0];
            float b1 = Bs[kk][tx * 4 + 1];
            float b2 = Bs[kk][tx * 4 + 2];
            float b3 = Bs[kk][tx * 4 + 3];
            acc[0][0] += a0 * b0; acc[0][1] += a0 * b1; acc[0][2] += a0 * b2; acc[0][3] += a0 * b3;
            acc[1][0] += a1 * b0; acc[1][1] += a1 * b1; acc[1][2] += a1 * b2; acc[1][3] += a1 * b3;
            acc[2][0] += a2 * b0; acc[2][1] += a2 * b1; acc[2][2] += a2 * b2; acc[2][3] += a2 * b3;
            acc[3][0] += a3 * b0; acc[3][1] += a3 * b1; acc[3][2] += a3 * b2; acc[3][3] += a3 * b3;
        }
    }

    // Epilogue: scatter into Q/K/V as [B][H][T][D]. Tile (64 cols) lies
    // entirely within one `which` and one head h (n0 is a multiple of 64).
    const int nbase = n0 + tx * 4;
    const int which = nbase >> 10;
    const int rem   = nbase & 1023;
    const int h     = rem >> 6;
    const int dbase = rem & 63;  // multiple of 4
    float* dst = (which == 0) ? Qb : ((which == 1) ? Kb : Vb);
    float bq0 = bias[nbase + 0], bq1 = bias[nbase + 1];
    float bq2 = bias[nbase + 2], bq3 = bias[nbase + 3];
    #pragma unroll
    for (int i = 0; i < 4; i++) {
        int m  = m0 + ty * 4 + i;
        int b_ = m >> 11;          // /T
        int tt = m & 2047;
        size_t idx = ((size_t)((b_ * Hn + h) * Tn + tt)) * Dn + dbase;
        float4 o;
        o.x = acc[i][0] + bq0;
        o.y = acc[i][1] + bq1;
        o.z = acc[i][2] + bq2;
        o.w = acc[i][3] + bq3;
        *(float4*)&dst[idx] = o;
    }
}

// ---------------------------------------------------------------------------
// Flash attention: one block = (head bh, 64-row Q tile). 64-key chunks.
// K stored transposed in LDS; P (probabilities) reuses the K-tile storage.
// ---------------------------------------------------------------------------
__global__ __launch_bounds__(256) void attn(
    const float* __restrict__ Qb, const float* __restrict__ Kb,
    const float* __restrict__ Vb, float* __restrict__ Ob)
{
    const int qt = blockIdx.x;   // 0..31
    const int bh = blockIdx.y;   // 0..63
    const int t  = threadIdx.x;
    const int r  = t >> 2;         // q-row 0..63 owned (shared by 4 threads)
    const int c0 = (t & 3) * 16;   // 16-wide column slice

    __shared__ float Qs[64][68];
    __shared__ float Kt[64][65];   // K^T [d][k]; later reused as P [row][k]
    __shared__ float Vs[64][68];
    __shared__ float row_alpha[64];
    __shared__ float row_scale[64];

    const float* Qg = Qb + ((size_t)bh * Tn + qt * 64) * Dn;

    #pragma unroll
    for (int i = 0; i < 4; i++) {
        int flat = i * 1024 + t * 4;
        int rr = flat >> 6, cc = flat & 63;
        float4 v = *(const float4*)&Qg[flat];
        v.x *= 0.125f; v.y *= 0.125f; v.z *= 0.125f; v.w *= 0.125f;  // D^-0.5
        *(float4*)&Qs[rr][cc] = v;
    }

    float Oa[16] = {};
    float m_r = -1e30f, l_r = 0.0f;   // only meaningful for t < 64

    for (int kt = 0; kt <= qt; kt++) {
        const float* Kg = Kb + ((size_t)bh * Tn + kt * 64) * Dn;
        const float* Vg = Vb + ((size_t)bh * Tn + kt * 64) * Dn;
        __syncthreads();  // prior-iteration P/V reads done (also covers Qs on iter 0)
        #pragma unroll
        for (int i = 0; i < 4; i++) {
            int flat = i * 1024 + t * 4;
            int rr = flat >> 6, cc = flat & 63;
            float4 kv = *(const float4*)&Kg[flat];
            Kt[cc + 0][rr] = kv.x;
            Kt[cc + 1][rr] = kv.y;
            Kt[cc + 2][rr] = kv.z;
            Kt[cc + 3][rr] = kv.w;
            *(float4*)&Vs[rr][cc] = *(const float4*)&Vg[flat];
        }
        __syncthreads();

        // scores for (row r, keys c0..c0+15)
        float s[16];
        #pragma unroll
        for (int j = 0; j < 16; j++) s[j] = 0.0f;
        #pragma unroll 4
        for (int d = 0; d < 64; d++) {
            float qv = Qs[r][d];
            #pragma unroll
            for (int j = 0; j < 16; j++) s[j] += qv * Kt[d][c0 + j];
        }
        if (kt == qt) {  // causal mask on the diagonal chunk
            #pragma unroll
            for (int j = 0; j < 16; j++)
                if (c0 + j > r) s[j] = -1e30f;
        }
        __syncthreads();  // all Kt (keys) reads done
        #pragma unroll
        for (int j = 0; j < 16; j++) Kt[r][c0 + j] = s[j];  // P-tile
        __syncthreads();

        if (t < 64) {  // online softmax, one thread per row
            float mx = m_r;
            for (int k = 0; k < 64; k++) mx = fmaxf(mx, Kt[t][k]);
            float alpha = __expf(m_r - mx);
            float sum = 0.0f;
            for (int k = 0; k < 64; k++) {
                float p = __expf(Kt[t][k] - mx);
                Kt[t][k] = p;
                sum += p;
            }
            l_r = l_r * alpha + sum;
            m_r = mx;
            row_alpha[t] = alpha;
        }
        __syncthreads();

        float alpha = row_alpha[r];
        #pragma unroll
        for (int j = 0; j < 16; j++) Oa[j] *= alpha;
        #pragma unroll 4
        for (int k = 0; k < 64; k++) {
            float pv = Kt[r][k];
            #pragma unroll
            for (int j = 0; j < 16; j++) Oa[j] += pv * Vs[k][c0 + j];
        }
    }

    if (t < 64) row_scale[t] = 1.0f / l_r;
    __syncthreads();
    float sc = row_scale[r];

    // write attn_out as [B*T][C] row-major: row (qt*64+r), cols h*64 + c0..
    const int b_ = bh >> 4, h = bh & 15;
    float* dst = Ob + ((size_t)(b_ * Tn + qt * 64 + r)) * Cn + h * 64 + c0;
    #pragma unroll
    for (int j = 0; j < 16; j += 4) {
        float4 o;
        o.x = Oa[j + 0] * sc;
        o.y = Oa[j + 1] * sc;
        o.z = Oa[j + 2] * sc;
        o.w = Oa[j + 3] * sc;
        *(float4*)&dst[j] = o;
    }
}

// ---------------------------------------------------------------------------
// GEMM 3: attn_out[8192,1024] @ o_w[1024,1024] + o_b -> out
// ---------------------------------------------------------------------------
__global__ __launch_bounds__(256) void out_gemm(
    const float* __restrict__ A, const float* __restrict__ W,
    const float* __restrict__ bias, float* __restrict__ Out)
{
    const int m0 = blockIdx.y * 64;
    const int n0 = blockIdx.x * 64;
    const int t  = threadIdx.x;
    const int tx = t & 15, ty = t >> 4;

    __shared__ float As[16][68];
    __shared__ float Bs[16][68];

    float acc[4][4] = {};

    const int amr = t >> 2,  akc = (t & 3) * 4;
    const int bkr = t >> 4,  bnc = (t & 15) * 4;

    for (int k0 = 0; k0 < 1024; k0 += 16) {
        float4 av = *(const float4*)&A[(size_t)(m0 + amr) * 1024 + k0 + akc];
        float4 bv = *(const float4*)&W[(size_t)(k0 + bkr) * 1024 + n0 + bnc];
        __syncthreads();
        As[akc + 0][amr] = av.x;
        As[akc + 1][amr] = av.y;
        As[akc + 2][amr] = av.z;
        As[akc + 3][amr] = av.w;
        *(float4*)&Bs[bkr][bnc] = bv;
        __syncthreads();
        #pragma unroll
        for (int kk = 0; kk < 16; kk++) {
            float a0 = As[kk][ty * 4 + 0];
            float a1 = As[kk][ty * 4 + 1];
            float a2 = As[kk][ty * 4 + 2];
            float a3 = As[kk][ty * 4 + 3];
            float b0 = Bs[kk][tx * 4 + 0];
            float b1 = Bs[kk][tx * 4 + 1];
            float b2 = Bs[kk][tx * 4 + 2];
            float b3 = Bs[kk][tx * 4 + 3];
            acc[0][0] += a0 * b0; acc[0][1] += a0 * b1; acc[0][2] += a0 * b2; acc[0][3] += a0 * b3;
            acc[1][0] += a1 * b0; acc[1][1] += a1 * b1; acc[1][2] += a1 * b2; acc[1][3] += a1 * b3;
            acc[2][0] += a2 * b0; acc[2][1] += a2 * b1; acc[2][2] += a2 * b2; acc[2][3] += a2 * b3;
            acc[3][0] += a3 * b0; acc[3][1] += a3 * b1; acc[3][2] += a3 * b2; acc[3][3] += a3 * b3;
        }
    }

    const int nbase = n0 + tx * 4;
    float bq0 = bias[nbase + 0], bq1 = bias[nbase + 1];
    float bq2 = bias[nbase + 2], bq3 = bias[nbase + 3];
    #pragma unroll
    for (int i = 0; i < 4; i++) {
        int m = m0 + ty * 4 + i;
        float4 o;
        o.x = acc[i][0] + bq0;
        o.y = acc[i][1] + bq1;
        o.z = acc[i][2] + bq2;
        o.w = acc[i][3] + bq3;
        *(float4*)&Out[(size_t)m * 1024 + nbase] = o;
    }
}

// ---------------------------------------------------------------------------
extern "C" void kernel_launch(void* const* d_in, const int* in_sizes, int n_in,
                              void* d_out, int out_size, void* d_ws, size_t ws_size,
                              hipStream_t stream) {
    const float* X     = (const float*)d_in[0];  // [B,T,C]
    const float* qkv_w = (const float*)d_in[1];  // [C,3C]
    const float* qkv_b = (const float*)d_in[2];  // [3C]
    const float* o_w   = (const float*)d_in[3];  // [C,C]
    const float* o_b   = (const float*)d_in[4];  // [C]
    float* out = (float*)d_out;                  // [B,T,C] fp32

    const size_t BTC = (size_t)Bn * Tn * Cn;     // 8388608
    float* Qb = (float*)d_ws;                    // [B,H,T,D]
    float* Kb = Qb + BTC;
    float* Vb = Kb + BTC;
    float* Ao = Vb + BTC;                        // [B*T, C]

    qkv_gemm<<<dim3(3072 / 64, 8192 / 64), 256, 0, stream>>>(X, qkv_w, qkv_b, Qb, Kb, Vb);
    attn<<<dim3(Tn / 64, Bn * Hn), 256, 0, stream>>>(Qb, Kb, Vb, Ao);
    out_gemm<<<dim3(1024 / 64, 8192 / 64), 256, 0, stream>>>(Ao, o_w, o_b, out);
}

// Round 2
// 1256.312 us; speedup vs baseline: 2.5822x; 2.5822x over previous
//
#include <hip/hip_runtime.h>
#include <hip/hip_bf16.h>

// Problem constants
#define Bn 4
#define Tn 2048
#define Cn 1024
#define Hn 16
#define Dn 64

typedef __bf16 bf16x8 __attribute__((ext_vector_type(8)));
typedef float f32x4 __attribute__((ext_vector_type(4)));
union B8 { uint4 u; bf16x8 f; ushort s[8]; };

static __device__ __forceinline__ ushort f2bf(float x) {
    __hip_bfloat16 h = __float2bfloat16(x);
    return *(ushort*)&h;
}

// ---------------------------------------------------------------------------
// GEMM 1: X[8192,1024] @ W[1024,3072] + b  -> bf16 Q/K/V in [B,H,T,D]
// (Q pre-scaled by D^-0.5). fp32 compute, 64x64 tile, 4x4 micro-tile.
// ---------------------------------------------------------------------------
__global__ __launch_bounds__(256) void qkv_gemm(
    const float* __restrict__ X, const float* __restrict__ W,
    const float* __restrict__ bias,
    ushort* __restrict__ Qb, ushort* __restrict__ Kb, ushort* __restrict__ Vb)
{
    const int m0 = blockIdx.y * 64;
    const int n0 = blockIdx.x * 64;
    const int t  = threadIdx.x;
    const int tx = t & 15, ty = t >> 4;

    __shared__ float As[16][68];
    __shared__ float Bs[16][68];

    float acc[4][4] = {};

    const int amr = t >> 2,  akc = (t & 3) * 4;
    const int bkr = t >> 4,  bnc = (t & 15) * 4;

    for (int k0 = 0; k0 < 1024; k0 += 16) {
        float4 av = *(const float4*)&X[(size_t)(m0 + amr) * 1024 + k0 + akc];
        float4 bv = *(const float4*)&W[(size_t)(k0 + bkr) * 3072 + n0 + bnc];
        __syncthreads();
        As[akc + 0][amr] = av.x;
        As[akc + 1][amr] = av.y;
        As[akc + 2][amr] = av.z;
        As[akc + 3][amr] = av.w;
        *(float4*)&Bs[bkr][bnc] = bv;
        __syncthreads();
        #pragma unroll
        for (int kk = 0; kk < 16; kk++) {
            float a0 = As[kk][ty * 4 + 0];
            float a1 = As[kk][ty * 4 + 1];
            float a2 = As[kk][ty * 4 + 2];
            float a3 = As[kk][ty * 4 + 3];
            float b0 = Bs[kk][tx * 4 + 0];
            float b1 = Bs[kk][tx * 4 + 1];
            float b2 = Bs[kk][tx * 4 + 2];
            float b3 = Bs[kk][tx * 4 + 3];
            acc[0][0] += a0 * b0; acc[0][1] += a0 * b1; acc[0][2] += a0 * b2; acc[0][3] += a0 * b3;
            acc[1][0] += a1 * b0; acc[1][1] += a1 * b1; acc[1][2] += a1 * b2; acc[1][3] += a1 * b3;
            acc[2][0] += a2 * b0; acc[2][1] += a2 * b1; acc[2][2] += a2 * b2; acc[2][3] += a2 * b3;
            acc[3][0] += a3 * b0; acc[3][1] += a3 * b1; acc[3][2] += a3 * b2; acc[3][3] += a3 * b3;
        }
    }

    const int nbase = n0 + tx * 4;
    const int which = nbase >> 10;
    const int rem   = nbase & 1023;
    const int h     = rem >> 6;
    const int dbase = rem & 63;
    ushort* dst = (which == 0) ? Qb : ((which == 1) ? Kb : Vb);
    const float scale = (which == 0) ? 0.125f : 1.0f;  // D^-0.5 folded into Q
    float bq0 = bias[nbase + 0], bq1 = bias[nbase + 1];
    float bq2 = bias[nbase + 2], bq3 = bias[nbase + 3];
    #pragma unroll
    for (int i = 0; i < 4; i++) {
        int m  = m0 + ty * 4 + i;
        int b_ = m >> 11;
        int tt = m & 2047;
        size_t idx = ((size_t)((b_ * Hn + h) * Tn + tt)) * Dn + dbase;
        ushort4 o;
        o.x = f2bf((acc[i][0] + bq0) * scale);
        o.y = f2bf((acc[i][1] + bq1) * scale);
        o.z = f2bf((acc[i][2] + bq2) * scale);
        o.w = f2bf((acc[i][3] + bq3) * scale);
        *(ushort4*)&dst[idx] = o;
    }
}

// ---------------------------------------------------------------------------
// MFMA flash attention. Block = (64 Q rows, one head). 4 waves, each owns
// 16 Q rows. K-chunks of 64 keys staged in LDS (K row-major, V transposed,
// stride 72 bf16 -> 2-way bank aliasing = free). Online softmax in C-layout,
// P round-trips LDS (C-layout -> A-layout).
// ---------------------------------------------------------------------------
__global__ __launch_bounds__(256) void attn_mfma(
    const ushort* __restrict__ Qb, const ushort* __restrict__ Kb,
    const ushort* __restrict__ Vb, float* __restrict__ Ob)
{
    const int qt   = blockIdx.x;     // 0..31
    const int bh   = blockIdx.y;     // 0..63
    const int t    = threadIdx.x;
    const int wave = t >> 6, lane = t & 63;
    const int ln   = lane & 15, quad = lane >> 4;

    __shared__ ushort Ks [64 * 72];      // K tile  [key][d]
    __shared__ ushort Vts[64 * 72];      // V^T     [d][key]
    __shared__ ushort Ps [4][16 * 72];   // per-wave P tile [row][key]

    // Q fragments (A-layout): row = ln, d = ks*32 + quad*8 + j
    const ushort* Qg = Qb + ((size_t)bh * Tn + qt * 64 + wave * 16) * Dn;
    bf16x8 qf[2];
    {
        B8 tmp;
        tmp.u = *(const uint4*)&Qg[(size_t)ln * 64 +  0 + quad * 8]; qf[0] = tmp.f;
        tmp.u = *(const uint4*)&Qg[(size_t)ln * 64 + 32 + quad * 8]; qf[1] = tmp.f;
    }

    f32x4 Oacc[4] = {};                  // O tile, 4 d-subtiles, C-layout
    float m_r[4], l_r[4];
    #pragma unroll
    for (int i = 0; i < 4; i++) { m_r[i] = -1e30f; l_r[i] = 0.0f; }

    const ushort* KgB = Kb + (size_t)bh * Tn * Dn;
    const ushort* VgB = Vb + (size_t)bh * Tn * Dn;

    for (int kt = 0; kt <= qt; kt++) {
        const ushort* Kg = KgB + kt * 64 * 64;
        const ushort* Vg = VgB + kt * 64 * 64;
        __syncthreads();   // prior chunk's K/V reads complete
        #pragma unroll
        for (int it = 0; it < 2; it++) {
            int flat = it * 256 + t;           // 0..511
            int key  = flat >> 3, dseg = flat & 7;
            uint4 kv = *(const uint4*)&Kg[key * 64 + dseg * 8];
            *(uint4*)&Ks[key * 72 + dseg * 8] = kv;
            B8 vv; vv.u = *(const uint4*)&Vg[key * 64 + dseg * 8];
            #pragma unroll
            for (int i = 0; i < 8; i++)
                Vts[(dseg * 8 + i) * 72 + key] = vv.s[i];
        }
        __syncthreads();

        // S = Q K^T : 4 key-subtiles x 2 k-steps
        f32x4 S[4] = {};
        #pragma unroll
        for (int ks = 0; ks < 2; ks++) {
            #pragma unroll
            for (int ct = 0; ct < 4; ct++) {
                B8 kf; kf.u = *(const uint4*)&Ks[(ct * 16 + ln) * 72 + ks * 32 + quad * 8];
                S[ct] = __builtin_amdgcn_mfma_f32_16x16x32_bf16(qf[ks], kf.f, S[ct], 0, 0, 0);
            }
        }

        if (kt == qt) {  // causal mask, diagonal chunk only
            const int rowbase = wave * 16 + quad * 4;
            #pragma unroll
            for (int ct = 0; ct < 4; ct++) {
                int key = ct * 16 + ln;
                #pragma unroll
                for (int reg = 0; reg < 4; reg++)
                    if (key > rowbase + reg) S[ct][reg] = -1e30f;
            }
        }

        // online softmax (rows in C-layout: row = quad*4+reg, col = ln)
        float mnew[4], alpha[4], rs[4];
        #pragma unroll
        for (int reg = 0; reg < 4; reg++) {
            float mx = fmaxf(fmaxf(S[0][reg], S[1][reg]), fmaxf(S[2][reg], S[3][reg]));
            #pragma unroll
            for (int off = 1; off < 16; off <<= 1)
                mx = fmaxf(mx, __shfl_xor(mx, off));
            mnew[reg]  = fmaxf(m_r[reg], mx);
            alpha[reg] = __expf(m_r[reg] - mnew[reg]);
            rs[reg]    = 0.0f;
        }
        ushort* Pw = Ps[wave];
        #pragma unroll
        for (int ct = 0; ct < 4; ct++) {
            #pragma unroll
            for (int reg = 0; reg < 4; reg++) {
                float p = __expf(S[ct][reg] - mnew[reg]);
                rs[reg] += p;
                Pw[(quad * 4 + reg) * 72 + ct * 16 + ln] = f2bf(p);
            }
        }
        #pragma unroll
        for (int reg = 0; reg < 4; reg++) {
            float s = rs[reg];
            #pragma unroll
            for (int off = 1; off < 16; off <<= 1)
                s += __shfl_xor(s, off);
            l_r[reg] = l_r[reg] * alpha[reg] + s;
            m_r[reg] = mnew[reg];
        }
        #pragma unroll
        for (int ct = 0; ct < 4; ct++)
            #pragma unroll
            for (int reg = 0; reg < 4; reg++)
                Oacc[ct][reg] *= alpha[reg];

        // O += P V : P A-layout from LDS, V^T B-layout from LDS
        #pragma unroll
        for (int ks = 0; ks < 2; ks++) {
            B8 pf; pf.u = *(const uint4*)&Pw[ln * 72 + ks * 32 + quad * 8];
            #pragma unroll
            for (int ct = 0; ct < 4; ct++) {
                B8 vf; vf.u = *(const uint4*)&Vts[(ct * 16 + ln) * 72 + ks * 32 + quad * 8];
                Oacc[ct] = __builtin_amdgcn_mfma_f32_16x16x32_bf16(pf.f, vf.f, Oacc[ct], 0, 0, 0);
            }
        }
    }

    // epilogue: write fp32 attn_out [B*T][C]
    const int b_ = bh >> 4, h = bh & 15;
    #pragma unroll
    for (int reg = 0; reg < 4; reg++) {
        float inv = 1.0f / l_r[reg];
        int row = qt * 64 + wave * 16 + quad * 4 + reg;
        float* dst = Ob + ((size_t)(b_ * Tn + row)) * Cn + h * 64;
        #pragma unroll
        for (int ct = 0; ct < 4; ct++)
            dst[ct * 16 + ln] = Oacc[ct][reg] * inv;
    }
}

// ---------------------------------------------------------------------------
// GEMM 3: attn_out[8192,1024] @ o_w[1024,1024] + o_b -> out (fp32)
// ---------------------------------------------------------------------------
__global__ __launch_bounds__(256) void out_gemm(
    const float* __restrict__ A, const float* __restrict__ W,
    const float* __restrict__ bias, float* __restrict__ Out)
{
    const int m0 = blockIdx.y * 64;
    const int n0 = blockIdx.x * 64;
    const int t  = threadIdx.x;
    const int tx = t & 15, ty = t >> 4;

    __shared__ float As[16][68];
    __shared__ float Bs[16][68];

    float acc[4][4] = {};

    const int amr = t >> 2,  akc = (t & 3) * 4;
    const int bkr = t >> 4,  bnc = (t & 15) * 4;

    for (int k0 = 0; k0 < 1024; k0 += 16) {
        float4 av = *(const float4*)&A[(size_t)(m0 + amr) * 1024 + k0 + akc];
        float4 bv = *(const float4*)&W[(size_t)(k0 + bkr) * 1024 + n0 + bnc];
        __syncthreads();
        As[akc + 0][amr] = av.x;
        As[akc + 1][amr] = av.y;
        As[akc + 2][amr] = av.z;
        As[akc + 3][amr] = av.w;
        *(float4*)&Bs[bkr][bnc] = bv;
        __syncthreads();
        #pragma unroll
        for (int kk = 0; kk < 16; kk++) {
            float a0 = As[kk][ty * 4 + 0];
            float a1 = As[kk][ty * 4 + 1];
            float a2 = As[kk][ty * 4 + 2];
            float a3 = As[kk][ty * 4 + 3];
            float b0 = Bs[kk][tx * 4 + 0];
            float b1 = Bs[kk][tx * 4 + 1];
            float b2 = Bs[kk][tx * 4 + 2];
            float b3 = Bs[kk][tx * 4 + 3];
            acc[0][0] += a0 * b0; acc[0][1] += a0 * b1; acc[0][2] += a0 * b2; acc[0][3] += a0 * b3;
            acc[1][0] += a1 * b0; acc[1][1] += a1 * b1; acc[1][2] += a1 * b2; acc[1][3] += a1 * b3;
            acc[2][0] += a2 * b0; acc[2][1] += a2 * b1; acc[2][2] += a2 * b2; acc[2][3] += a2 * b3;
            acc[3][0] += a3 * b0; acc[3][1] += a3 * b1; acc[3][2] += a3 * b2; acc[3][3] += a3 * b3;
        }
    }

    const int nbase = n0 + tx * 4;
    float bq0 = bias[nbase + 0], bq1 = bias[nbase + 1];
    float bq2 = bias[nbase + 2], bq3 = bias[nbase + 3];
    #pragma unroll
    for (int i = 0; i < 4; i++) {
        int m = m0 + ty * 4 + i;
        float4 o;
        o.x = acc[i][0] + bq0;
        o.y = acc[i][1] + bq1;
        o.z = acc[i][2] + bq2;
        o.w = acc[i][3] + bq3;
        *(float4*)&Out[(size_t)m * 1024 + nbase] = o;
    }
}

// ---------------------------------------------------------------------------
extern "C" void kernel_launch(void* const* d_in, const int* in_sizes, int n_in,
                              void* d_out, int out_size, void* d_ws, size_t ws_size,
                              hipStream_t stream) {
    const float* X     = (const float*)d_in[0];
    const float* qkv_w = (const float*)d_in[1];
    const float* qkv_b = (const float*)d_in[2];
    const float* o_w   = (const float*)d_in[3];
    const float* o_b   = (const float*)d_in[4];
    float* out = (float*)d_out;

    const size_t BTC = (size_t)Bn * Tn * Cn;     // 8388608
    ushort* Qb = (ushort*)d_ws;                  // bf16 [B,H,T,D]
    ushort* Kb = Qb + BTC;
    ushort* Vb = Kb + BTC;
    float*  Ao = (float*)(Vb + BTC);             // fp32 [B*T, C]

    qkv_gemm<<<dim3(3072 / 64, 8192 / 64), 256, 0, stream>>>(X, qkv_w, qkv_b, Qb, Kb, Vb);
    attn_mfma<<<dim3(Tn / 64, Bn * Hn), 256, 0, stream>>>(Qb, Kb, Vb, Ao);
    out_gemm<<<dim3(1024 / 64, 8192 / 64), 256, 0, stream>>>(Ao, o_w, o_b, out);
}

// Round 3
// 492.128 us; speedup vs baseline: 6.5918x; 2.5528x over previous
//
#include <hip/hip_runtime.h>
#include <hip/hip_bf16.h>

// Problem constants
#define Bn 4
#define Tn 2048
#define Cn 1024
#define Hn 16
#define Dn 64
#define Kdim 1024

typedef __bf16 bf16x8 __attribute__((ext_vector_type(8)));
typedef float f32x4 __attribute__((ext_vector_type(4)));
union B8 { uint4 u; bf16x8 f; ushort s[8]; };

static __device__ __forceinline__ ushort f2bf(float x) {
    __hip_bfloat16 h = __float2bfloat16(x);
    return *(ushort*)&h;
}

#define AS1 __attribute__((address_space(1)))
#define AS3 __attribute__((address_space(3)))

static __device__ __forceinline__ void gload_lds16(const ushort* g, ushort* l) {
    __builtin_amdgcn_global_load_lds((AS1 const uint4*)(const void*)g,
                                     (AS3 uint4*)(void*)l, 16, 0, 0);
}

// ---------------------------------------------------------------------------
// fp32 -> bf16 cast (layout preserved). n multiple of 8.
// ---------------------------------------------------------------------------
__global__ __launch_bounds__(256) void cvt_bf16(
    const float* __restrict__ src, ushort* __restrict__ dst, int n)
{
    int i = (blockIdx.x * 256 + threadIdx.x) * 8;
    if (i >= n) return;
    float4 a = *(const float4*)&src[i];
    float4 b = *(const float4*)&src[i + 4];
    ushort4 o0, o1;
    o0.x = f2bf(a.x); o0.y = f2bf(a.y); o0.z = f2bf(a.z); o0.w = f2bf(a.w);
    o1.x = f2bf(b.x); o1.y = f2bf(b.y); o1.z = f2bf(b.z); o1.w = f2bf(b.w);
    *(ushort4*)&dst[i] = o0;
    *(ushort4*)&dst[i + 4] = o1;
}

// ---------------------------------------------------------------------------
// W[K,N] fp32 -> Wt[N,K] bf16 (32x32 LDS tile transpose)
// ---------------------------------------------------------------------------
__global__ __launch_bounds__(256) void transpose_bf16(
    const float* __restrict__ W, ushort* __restrict__ Wt, int N)
{
    __shared__ float Ls[32][33];
    const int k0 = blockIdx.y * 32, n0 = blockIdx.x * 32;
    const int tx = threadIdx.x & 31, ty = threadIdx.x >> 5;  // ty 0..7
    #pragma unroll
    for (int i = 0; i < 4; i++) {
        int r = ty + i * 8;
        Ls[r][tx] = W[(size_t)(k0 + r) * N + n0 + tx];
    }
    __syncthreads();
    #pragma unroll
    for (int i = 0; i < 4; i++) {
        int r = ty + i * 8;
        Wt[(size_t)(n0 + r) * Kdim + k0 + tx] = f2bf(Ls[tx][r]);
    }
}

// ---------------------------------------------------------------------------
// bf16 MFMA GEMM, m97 structure: C[M,N] = A[M,K] @ Bt[N,K]^T (+bias).
// 128x128 tile, BK=64, 256 threads (4 waves, 2x2), 4x4 16x16x32 acc/wave.
// global_load_lds width=16 staging, XOR-swizzled chunks (conflict-free).
// EPI 0: fp32 out [M,1024] + bias.  EPI 1: bf16 scatter to Q/K/V (+bias,
// Q pre-scaled by D^-0.5).
// ---------------------------------------------------------------------------
template <int EPI>
__global__ __launch_bounds__(256) void gemm_bt(
    const ushort* __restrict__ A, const ushort* __restrict__ Bt,
    const float* __restrict__ bias,
    float* __restrict__ Out, ushort* __restrict__ Qb,
    ushort* __restrict__ Kb, ushort* __restrict__ Vb)
{
    const int m0 = blockIdx.y * 128;
    const int n0 = blockIdx.x * 128;
    const int t  = threadIdx.x;
    const int wave = t >> 6, lane = t & 63;
    const int ln = lane & 15, quad = lane >> 4;
    const int wm = wave >> 1, wn = wave & 1;

    __shared__ ushort As[128 * 64];  // 16 KB, chunk c (16B) at As[c*8]
    __shared__ ushort Bs[128 * 64];

    f32x4 acc[4][4] = {};

    for (int k0 = 0; k0 < Kdim; k0 += 64) {
        __syncthreads();  // previous iter's fragment reads done
        #pragma unroll
        for (int it = 0; it < 4; it++) {
            int c = it * 256 + wave * 64 + lane;    // 0..1023
            int row = c >> 3, seg = c & 7;
            int gseg = seg ^ (row & 7);             // global-side swizzle
            gload_lds16(&A [(size_t)(m0 + row) * Kdim + k0 + gseg * 8], &As[c * 8]);
            gload_lds16(&Bt[(size_t)(n0 + row) * Kdim + k0 + gseg * 8], &Bs[c * 8]);
        }
        __syncthreads();  // staging complete (vmcnt drained by barrier)

        #pragma unroll
        for (int ks = 0; ks < 2; ks++) {
            bf16x8 af[4], bf[4];
            #pragma unroll
            for (int mm = 0; mm < 4; mm++) {
                int row = wm * 64 + mm * 16 + ln;
                int seg = (ks * 4 + quad) ^ (ln & 7);
                B8 tmp; tmp.u = *(const uint4*)&As[row * 64 + seg * 8];
                af[mm] = tmp.f;
            }
            #pragma unroll
            for (int nn = 0; nn < 4; nn++) {
                int row = wn * 64 + nn * 16 + ln;
                int seg = (ks * 4 + quad) ^ (ln & 7);
                B8 tmp; tmp.u = *(const uint4*)&Bs[row * 64 + seg * 8];
                bf[nn] = tmp.f;
            }
            #pragma unroll
            for (int mm = 0; mm < 4; mm++)
                #pragma unroll
                for (int nn = 0; nn < 4; nn++)
                    acc[mm][nn] = __builtin_amdgcn_mfma_f32_16x16x32_bf16(
                        af[mm], bf[nn], acc[mm][nn], 0, 0, 0);
        }
    }

    if (EPI == 0) {
        // fp32 out [M,1024] + bias
        #pragma unroll
        for (int nn = 0; nn < 4; nn++) {
            int n = n0 + wn * 64 + nn * 16 + ln;
            float bv = bias[n];
            #pragma unroll
            for (int mm = 0; mm < 4; mm++) {
                int mbase = m0 + wm * 64 + mm * 16 + quad * 4;
                #pragma unroll
                for (int reg = 0; reg < 4; reg++)
                    Out[(size_t)(mbase + reg) * 1024 + n] = acc[mm][nn][reg] + bv;
            }
        }
    } else {
        // bf16 scatter to Q/K/V [B,H,T,D]; wave's 64 n-cols = one head
        const int nb = n0 + wn * 64;
        const int which = nb >> 10;
        const int h = (nb & 1023) >> 6;
        ushort* dst = (which == 0) ? Qb : ((which == 1) ? Kb : Vb);
        const float scale = (which == 0) ? 0.125f : 1.0f;
        #pragma unroll
        for (int nn = 0; nn < 4; nn++) {
            int n = nb + nn * 16 + ln;
            float bv = bias[n];
            #pragma unroll
            for (int mm = 0; mm < 4; mm++) {
                int mbase = m0 + wm * 64 + mm * 16 + quad * 4;
                #pragma unroll
                for (int reg = 0; reg < 4; reg++) {
                    int m = mbase + reg;
                    int b_ = m >> 11, tt = m & 2047;
                    dst[((size_t)((b_ * Hn + h) * Tn + tt)) * Dn + nn * 16 + ln] =
                        f2bf((acc[mm][nn][reg] + bv) * scale);
                }
            }
        }
    }
}

// ---------------------------------------------------------------------------
// MFMA flash attention (round-1 structure, bf16 output).
// ---------------------------------------------------------------------------
__global__ __launch_bounds__(256) void attn_mfma(
    const ushort* __restrict__ Qb, const ushort* __restrict__ Kb,
    const ushort* __restrict__ Vb, ushort* __restrict__ Ob)
{
    const int qt   = blockIdx.x;
    const int bh   = blockIdx.y;
    const int t    = threadIdx.x;
    const int wave = t >> 6, lane = t & 63;
    const int ln   = lane & 15, quad = lane >> 4;

    __shared__ ushort Ks [64 * 72];
    __shared__ ushort Vts[64 * 72];
    __shared__ ushort Ps [4][16 * 72];

    const ushort* Qg = Qb + ((size_t)bh * Tn + qt * 64 + wave * 16) * Dn;
    bf16x8 qf[2];
    {
        B8 tmp;
        tmp.u = *(const uint4*)&Qg[(size_t)ln * 64 +  0 + quad * 8]; qf[0] = tmp.f;
        tmp.u = *(const uint4*)&Qg[(size_t)ln * 64 + 32 + quad * 8]; qf[1] = tmp.f;
    }

    f32x4 Oacc[4] = {};
    float m_r[4], l_r[4];
    #pragma unroll
    for (int i = 0; i < 4; i++) { m_r[i] = -1e30f; l_r[i] = 0.0f; }

    const ushort* KgB = Kb + (size_t)bh * Tn * Dn;
    const ushort* VgB = Vb + (size_t)bh * Tn * Dn;

    for (int kt = 0; kt <= qt; kt++) {
        const ushort* Kg = KgB + kt * 64 * 64;
        const ushort* Vg = VgB + kt * 64 * 64;
        __syncthreads();
        #pragma unroll
        for (int it = 0; it < 2; it++) {
            int flat = it * 256 + t;
            int key  = flat >> 3, dseg = flat & 7;
            uint4 kv = *(const uint4*)&Kg[key * 64 + dseg * 8];
            *(uint4*)&Ks[key * 72 + dseg * 8] = kv;
            B8 vv; vv.u = *(const uint4*)&Vg[key * 64 + dseg * 8];
            #pragma unroll
            for (int i = 0; i < 8; i++)
                Vts[(dseg * 8 + i) * 72 + key] = vv.s[i];
        }
        __syncthreads();

        f32x4 S[4] = {};
        #pragma unroll
        for (int ks = 0; ks < 2; ks++) {
            #pragma unroll
            for (int ct = 0; ct < 4; ct++) {
                B8 kf; kf.u = *(const uint4*)&Ks[(ct * 16 + ln) * 72 + ks * 32 + quad * 8];
                S[ct] = __builtin_amdgcn_mfma_f32_16x16x32_bf16(qf[ks], kf.f, S[ct], 0, 0, 0);
            }
        }

        if (kt == qt) {
            const int rowbase = wave * 16 + quad * 4;
            #pragma unroll
            for (int ct = 0; ct < 4; ct++) {
                int key = ct * 16 + ln;
                #pragma unroll
                for (int reg = 0; reg < 4; reg++)
                    if (key > rowbase + reg) S[ct][reg] = -1e30f;
            }
        }

        float mnew[4], alpha[4], rs[4];
        #pragma unroll
        for (int reg = 0; reg < 4; reg++) {
            float mx = fmaxf(fmaxf(S[0][reg], S[1][reg]), fmaxf(S[2][reg], S[3][reg]));
            #pragma unroll
            for (int off = 1; off < 16; off <<= 1)
                mx = fmaxf(mx, __shfl_xor(mx, off));
            mnew[reg]  = fmaxf(m_r[reg], mx);
            alpha[reg] = __expf(m_r[reg] - mnew[reg]);
            rs[reg]    = 0.0f;
        }
        ushort* Pw = Ps[wave];
        #pragma unroll
        for (int ct = 0; ct < 4; ct++) {
            #pragma unroll
            for (int reg = 0; reg < 4; reg++) {
                float p = __expf(S[ct][reg] - mnew[reg]);
                rs[reg] += p;
                Pw[(quad * 4 + reg) * 72 + ct * 16 + ln] = f2bf(p);
            }
        }
        #pragma unroll
        for (int reg = 0; reg < 4; reg++) {
            float s = rs[reg];
            #pragma unroll
            for (int off = 1; off < 16; off <<= 1)
                s += __shfl_xor(s, off);
            l_r[reg] = l_r[reg] * alpha[reg] + s;
            m_r[reg] = mnew[reg];
        }
        #pragma unroll
        for (int ct = 0; ct < 4; ct++)
            #pragma unroll
            for (int reg = 0; reg < 4; reg++)
                Oacc[ct][reg] *= alpha[reg];

        #pragma unroll
        for (int ks = 0; ks < 2; ks++) {
            B8 pf; pf.u = *(const uint4*)&Pw[ln * 72 + ks * 32 + quad * 8];
            #pragma unroll
            for (int ct = 0; ct < 4; ct++) {
                B8 vf; vf.u = *(const uint4*)&Vts[(ct * 16 + ln) * 72 + ks * 32 + quad * 8];
                Oacc[ct] = __builtin_amdgcn_mfma_f32_16x16x32_bf16(pf.f, vf.f, Oacc[ct], 0, 0, 0);
            }
        }
    }

    // epilogue: bf16 attn_out [B*T][C]
    const int b_ = bh >> 4, h = bh & 15;
    #pragma unroll
    for (int reg = 0; reg < 4; reg++) {
        float inv = 1.0f / l_r[reg];
        int row = qt * 64 + wave * 16 + quad * 4 + reg;
        ushort* dst = Ob + ((size_t)(b_ * Tn + row)) * Cn + h * 64;
        #pragma unroll
        for (int ct = 0; ct < 4; ct++)
            dst[ct * 16 + ln] = f2bf(Oacc[ct][reg] * inv);
    }
}

// ---------------------------------------------------------------------------
extern "C" void kernel_launch(void* const* d_in, const int* in_sizes, int n_in,
                              void* d_out, int out_size, void* d_ws, size_t ws_size,
                              hipStream_t stream) {
    const float* X     = (const float*)d_in[0];
    const float* qkv_w = (const float*)d_in[1];
    const float* qkv_b = (const float*)d_in[2];
    const float* o_w   = (const float*)d_in[3];
    const float* o_b   = (const float*)d_in[4];
    float* out = (float*)d_out;

    const size_t BTC = (size_t)Bn * Tn * Cn;     // 8388608
    ushort* Xb  = (ushort*)d_ws;                 // bf16 [8192,1024]
    ushort* Wqt = Xb  + BTC;                     // bf16 [3072,1024]
    ushort* Wot = Wqt + 3 * Cn * Cn;             // bf16 [1024,1024]
    ushort* Qb  = Wot + Cn * Cn;                 // bf16 [B,H,T,D]
    ushort* Kb  = Qb  + BTC;
    ushort* Vb  = Kb  + BTC;
    ushort* Ao  = Vb  + BTC;                     // bf16 [B*T,C]

    cvt_bf16<<<dim3((int)(BTC / 8 / 256)), 256, 0, stream>>>(X, Xb, (int)BTC);
    transpose_bf16<<<dim3(3 * Cn / 32, Kdim / 32), 256, 0, stream>>>(qkv_w, Wqt, 3 * Cn);
    transpose_bf16<<<dim3(Cn / 32, Kdim / 32), 256, 0, stream>>>(o_w, Wot, Cn);

    gemm_bt<1><<<dim3(3 * Cn / 128, 8192 / 128), 256, 0, stream>>>(
        Xb, Wqt, qkv_b, nullptr, Qb, Kb, Vb);
    attn_mfma<<<dim3(Tn / 64, Bn * Hn), 256, 0, stream>>>(Qb, Kb, Vb, Ao);
    gemm_bt<0><<<dim3(Cn / 128, 8192 / 128), 256, 0, stream>>>(
        Ao, Wot, o_b, out, nullptr, nullptr, nullptr);
}

// Round 4
// 359.528 us; speedup vs baseline: 9.0230x; 1.3688x over previous
//
#include <hip/hip_runtime.h>
#include <hip/hip_bf16.h>

// Problem constants
#define Bn 4
#define Tn 2048
#define Cn 1024
#define Hn 16
#define Dn 64
#define Kdim 1024

typedef __bf16 bf16x8 __attribute__((ext_vector_type(8)));
typedef float f32x4 __attribute__((ext_vector_type(4)));
union B8 { uint4 u; bf16x8 f; ushort s[8]; };

static __device__ __forceinline__ ushort f2bf(float x) {
    __hip_bfloat16 h = __float2bfloat16(x);
    return *(ushort*)&h;
}

#define AS1 __attribute__((address_space(1)))
#define AS3 __attribute__((address_space(3)))

static __device__ __forceinline__ void gload_lds16(const ushort* g, ushort* l) {
    __builtin_amdgcn_global_load_lds((AS1 const uint4*)(const void*)g,
                                     (AS3 uint4*)(void*)l, 16, 0, 0);
}

// ---------------------------------------------------------------------------
// fp32 -> bf16 cast (layout preserved). n multiple of 8.
// ---------------------------------------------------------------------------
__global__ __launch_bounds__(256) void cvt_bf16(
    const float* __restrict__ src, ushort* __restrict__ dst, int n)
{
    int i = (blockIdx.x * 256 + threadIdx.x) * 8;
    if (i >= n) return;
    float4 a = *(const float4*)&src[i];
    float4 b = *(const float4*)&src[i + 4];
    ushort4 o0, o1;
    o0.x = f2bf(a.x); o0.y = f2bf(a.y); o0.z = f2bf(a.z); o0.w = f2bf(a.w);
    o1.x = f2bf(b.x); o1.y = f2bf(b.y); o1.z = f2bf(b.z); o1.w = f2bf(b.w);
    *(ushort4*)&dst[i] = o0;
    *(ushort4*)&dst[i + 4] = o1;
}

// ---------------------------------------------------------------------------
// W[K,N] fp32 -> Wt[N,K] bf16 (32x32 LDS tile transpose)
// ---------------------------------------------------------------------------
__global__ __launch_bounds__(256) void transpose_bf16(
    const float* __restrict__ W, ushort* __restrict__ Wt, int N)
{
    __shared__ float Ls[32][33];
    const int k0 = blockIdx.y * 32, n0 = blockIdx.x * 32;
    const int tx = threadIdx.x & 31, ty = threadIdx.x >> 5;
    #pragma unroll
    for (int i = 0; i < 4; i++) {
        int r = ty + i * 8;
        Ls[r][tx] = W[(size_t)(k0 + r) * N + n0 + tx];
    }
    __syncthreads();
    #pragma unroll
    for (int i = 0; i < 4; i++) {
        int r = ty + i * 8;
        Wt[(size_t)(n0 + r) * Kdim + k0 + tx] = f2bf(Ls[tx][r]);
    }
}

// ---------------------------------------------------------------------------
// bf16 MFMA GEMM (m97 structure): C[M,N] = A[M,K] @ Bt[N,K]^T (+bias).
// EPI 0: fp32 out + bias.  EPI 1: bf16 Q[B,H,T,D] (pre-scaled), K[B,H,T,D],
// V^T [B,H,D,T] (vectorized ushort4 token-contiguous stores).
// ---------------------------------------------------------------------------
template <int EPI>
__global__ __launch_bounds__(256) void gemm_bt(
    const ushort* __restrict__ A, const ushort* __restrict__ Bt,
    const float* __restrict__ bias,
    float* __restrict__ Out, ushort* __restrict__ Qb,
    ushort* __restrict__ Kb, ushort* __restrict__ Vtb)
{
    const int m0 = blockIdx.y * 128;
    const int n0 = blockIdx.x * 128;
    const int t  = threadIdx.x;
    const int wave = t >> 6, lane = t & 63;
    const int ln = lane & 15, quad = lane >> 4;
    const int wm = wave >> 1, wn = wave & 1;

    __shared__ ushort As[128 * 64];
    __shared__ ushort Bs[128 * 64];

    f32x4 acc[4][4] = {};

    for (int k0 = 0; k0 < Kdim; k0 += 64) {
        __syncthreads();
        #pragma unroll
        for (int it = 0; it < 4; it++) {
            int c = it * 256 + wave * 64 + lane;
            int row = c >> 3, seg = c & 7;
            int gseg = seg ^ (row & 7);
            gload_lds16(&A [(size_t)(m0 + row) * Kdim + k0 + gseg * 8], &As[c * 8]);
            gload_lds16(&Bt[(size_t)(n0 + row) * Kdim + k0 + gseg * 8], &Bs[c * 8]);
        }
        __syncthreads();

        #pragma unroll
        for (int ks = 0; ks < 2; ks++) {
            bf16x8 af[4], bf[4];
            #pragma unroll
            for (int mm = 0; mm < 4; mm++) {
                int row = wm * 64 + mm * 16 + ln;
                int seg = (ks * 4 + quad) ^ (ln & 7);
                B8 tmp; tmp.u = *(const uint4*)&As[row * 64 + seg * 8];
                af[mm] = tmp.f;
            }
            #pragma unroll
            for (int nn = 0; nn < 4; nn++) {
                int row = wn * 64 + nn * 16 + ln;
                int seg = (ks * 4 + quad) ^ (ln & 7);
                B8 tmp; tmp.u = *(const uint4*)&Bs[row * 64 + seg * 8];
                bf[nn] = tmp.f;
            }
            #pragma unroll
            for (int mm = 0; mm < 4; mm++)
                #pragma unroll
                for (int nn = 0; nn < 4; nn++)
                    acc[mm][nn] = __builtin_amdgcn_mfma_f32_16x16x32_bf16(
                        af[mm], bf[nn], acc[mm][nn], 0, 0, 0);
        }
    }

    if (EPI == 0) {
        #pragma unroll
        for (int nn = 0; nn < 4; nn++) {
            int n = n0 + wn * 64 + nn * 16 + ln;
            float bv = bias[n];
            #pragma unroll
            for (int mm = 0; mm < 4; mm++) {
                int mbase = m0 + wm * 64 + mm * 16 + quad * 4;
                #pragma unroll
                for (int reg = 0; reg < 4; reg++)
                    Out[(size_t)(mbase + reg) * 1024 + n] = acc[mm][nn][reg] + bv;
            }
        }
    } else {
        const int nb = n0 + wn * 64;
        const int which = nb >> 10;            // 0=Q 1=K 2=V
        const int h = (nb & 1023) >> 6;
        const float scale = (which == 0) ? 0.125f : 1.0f;
        #pragma unroll
        for (int nn = 0; nn < 4; nn++) {
            int n = nb + nn * 16 + ln;
            float bv = bias[n];
            #pragma unroll
            for (int mm = 0; mm < 4; mm++) {
                int mbase = m0 + wm * 64 + mm * 16 + quad * 4;
                int b_ = mbase >> 11, tt = mbase & 2047;
                if (which == 2) {
                    ushort4 o;
                    #pragma unroll
                    for (int reg = 0; reg < 4; reg++)
                        ((ushort*)&o)[reg] = f2bf(acc[mm][nn][reg] + bv);
                    *(ushort4*)&Vtb[((size_t)((b_ * Hn + h) * Dn) + nn * 16 + ln) * Tn + tt] = o;
                } else {
                    ushort* dst = (which == 0) ? Qb : Kb;
                    #pragma unroll
                    for (int reg = 0; reg < 4; reg++)
                        dst[((size_t)((b_ * Hn + h) * Tn + tt + reg)) * Dn + nn * 16 + ln] =
                            f2bf((acc[mm][nn][reg] + bv) * scale);
                }
            }
        }
    }
}

// ---------------------------------------------------------------------------
// Flash attention v2: S^T/O^T formulation. Block = 128 Q rows (4 waves x 32q),
// K-chunk 128. Per-lane softmax stats (q = lane). K [key][d] and V^T [d][key]
// staged via global_load_lds w/ XOR swizzle; P per-wave half-buffer [32][66].
// Block handles q-tiles `pair` and `15-pair` (constant 17 chunks).
// ---------------------------------------------------------------------------
__global__ __launch_bounds__(256) void attn_mfma(
    const ushort* __restrict__ Qb, const ushort* __restrict__ Kb,
    const ushort* __restrict__ Vtb, ushort* __restrict__ Ob)
{
    const int pair = blockIdx.x;   // 0..7
    const int bh   = blockIdx.y;   // 0..63
    const int t    = threadIdx.x;
    const int wave = t >> 6, lane = t & 63;
    const int ln   = lane & 15, quad = lane >> 4;

    __shared__ ushort Ks[128 * 64];     // [key][d], 16 KB, xor-swizzled segs
    __shared__ ushort Vs[64 * 128];     // [d][key], 16 KB, xor-swizzled segs
    __shared__ ushort Ps[4][32 * 66];   // per-wave P half [q][key(64)+pad]

    const ushort* KgB = Kb  + (size_t)bh * Tn * Dn;
    const ushort* VgB = Vtb + (size_t)bh * Dn * Tn;
    const int b_ = bh >> 4, h = bh & 15;

    for (int tile = 0; tile < 2; tile++) {
        const int qt = (tile == 0) ? pair : 15 - pair;
        const int q0 = qt * 128;

        // Q B-fragments: B[k=d][n=q], lane ln = q, d = ks*32+quad*8+j
        const ushort* Qg = Qb + ((size_t)bh * Tn + q0 + wave * 32) * Dn;
        bf16x8 qf[2][2];
        #pragma unroll
        for (int ns = 0; ns < 2; ns++)
            #pragma unroll
            for (int ks = 0; ks < 2; ks++) {
                B8 tmp; tmp.u = *(const uint4*)&Qg[(ns * 16 + ln) * 64 + ks * 32 + quad * 8];
                qf[ns][ks] = tmp.f;
            }

        f32x4 Oacc[4][2] = {};   // O^T [d-subtile][ns], lane ln = q
        float m_r[2] = {-1e30f, -1e30f}, l_r[2] = {0.f, 0.f};

        for (int kc = 0; kc <= qt; kc++) {
            __syncthreads();   // prior chunk's fragment reads done
            #pragma unroll
            for (int it = 0; it < 4; it++) {     // K chunk: 1024 x 16B
                int c = it * 256 + wave * 64 + lane;
                int row = c >> 3, seg = c & 7;
                int gs = seg ^ (row & 7);
                gload_lds16(&KgB[(size_t)(kc * 128 + row) * Dn + gs * 8], &Ks[c * 8]);
            }
            #pragma unroll
            for (int it = 0; it < 4; it++) {     // V^T chunk: 1024 x 16B
                int c = it * 256 + wave * 64 + lane;
                int row = c >> 4, seg = c & 15;
                int gs = (seg & 8) | ((seg & 7) ^ (row & 7));
                gload_lds16(&VgB[(size_t)row * Tn + kc * 128 + gs * 8], &Vs[c * 8]);
            }
            __syncthreads();

            // S^T = K Q^T: rows = keys (128 = 8 ct), cols = q (32 = 2 ns)
            f32x4 S[8][2] = {};
            #pragma unroll
            for (int ks = 0; ks < 2; ks++)
                #pragma unroll
                for (int ct = 0; ct < 8; ct++) {
                    B8 a; a.u = *(const uint4*)&Ks[(ct * 16 + ln) * 64 +
                                                   (((ks * 4 + quad) ^ (ln & 7)) * 8)];
                    #pragma unroll
                    for (int ns = 0; ns < 2; ns++)
                        S[ct][ns] = __builtin_amdgcn_mfma_f32_16x16x32_bf16(
                            a.f, qf[ns][ks], S[ct][ns], 0, 0, 0);
                }

            if (kc == qt) {   // causal mask on diagonal chunk
                #pragma unroll
                for (int ct = 0; ct < 8; ct++) {
                    int keyl = ct * 16 + quad * 4;
                    #pragma unroll
                    for (int ns = 0; ns < 2; ns++) {
                        int ql = wave * 32 + ns * 16 + ln;
                        #pragma unroll
                        for (int reg = 0; reg < 4; reg++)
                            if (keyl + reg > ql) S[ct][ns][reg] = -1e30f;
                    }
                }
            }

            // per-lane online softmax stats (row q = ln; reduce over quads)
            float alpha[2], ssum[2] = {0.f, 0.f};
            #pragma unroll
            for (int ns = 0; ns < 2; ns++) {
                float pm = -1e30f;
                #pragma unroll
                for (int ct = 0; ct < 8; ct++)
                    #pragma unroll
                    for (int reg = 0; reg < 4; reg++)
                        pm = fmaxf(pm, S[ct][ns][reg]);
                pm = fmaxf(pm, __shfl_xor(pm, 16));
                pm = fmaxf(pm, __shfl_xor(pm, 32));
                float mn = fmaxf(m_r[ns], pm);
                alpha[ns] = __expf(m_r[ns] - mn);
                m_r[ns] = mn;
                #pragma unroll
                for (int ctd = 0; ctd < 4; ctd++)
                    Oacc[ctd][ns] *= alpha[ns];
            }

            ushort* Pw = Ps[wave];
            #pragma unroll
            for (int pass = 0; pass < 2; pass++) {
                // exp + write P half (keys pass*64 .. +63), b64 stores
                #pragma unroll
                for (int ct_h = 0; ct_h < 4; ct_h++) {
                    int ct = pass * 4 + ct_h;
                    #pragma unroll
                    for (int ns = 0; ns < 2; ns++) {
                        ushort4 o;
                        #pragma unroll
                        for (int reg = 0; reg < 4; reg++) {
                            float p = __expf(S[ct][ns][reg] - m_r[ns]);
                            ssum[ns] += p;
                            ((ushort*)&o)[reg] = f2bf(p);
                        }
                        *(ushort4*)&Pw[(ns * 16 + ln) * 66 + ct_h * 16 + quad * 4] = o;
                    }
                }
                // O^T += V^T P^T over this half's 64 keys
                #pragma unroll
                for (int kh = 0; kh < 2; kh++) {
                    int gks = pass * 2 + kh;       // global 32-key step
                    B8 vfr[4];
                    #pragma unroll
                    for (int ctd = 0; ctd < 4; ctd++) {
                        int gs = gks * 4 + quad;
                        int lseg = (gs & 8) | ((gs & 7) ^ (ln & 7));
                        vfr[ctd].u = *(const uint4*)&Vs[(ctd * 16 + ln) * 128 + lseg * 8];
                    }
                    #pragma unroll
                    for (int ns = 0; ns < 2; ns++) {
                        B8 pfr; pfr.u = *(const uint4*)&Pw[(ns * 16 + ln) * 66 +
                                                           kh * 32 + quad * 8];
                        #pragma unroll
                        for (int ctd = 0; ctd < 4; ctd++)
                            Oacc[ctd][ns] = __builtin_amdgcn_mfma_f32_16x16x32_bf16(
                                vfr[ctd].f, pfr.f, Oacc[ctd][ns], 0, 0, 0);
                    }
                }
            }
            #pragma unroll
            for (int ns = 0; ns < 2; ns++) {
                float s = ssum[ns];
                s += __shfl_xor(s, 16);
                s += __shfl_xor(s, 32);
                l_r[ns] = l_r[ns] * alpha[ns] + s;
            }
        }

        // epilogue: bf16 attn_out [B*T][C]; lane ln = token, regs = d
        #pragma unroll
        for (int ns = 0; ns < 2; ns++) {
            float inv = 1.0f / l_r[ns];
            int token = q0 + wave * 32 + ns * 16 + ln;
            ushort* dst = Ob + ((size_t)(b_ * Tn + token)) * Cn + h * 64;
            #pragma unroll
            for (int ctd = 0; ctd < 4; ctd++) {
                ushort4 o;
                #pragma unroll
                for (int reg = 0; reg < 4; reg++)
                    ((ushort*)&o)[reg] = f2bf(Oacc[ctd][ns][reg] * inv);
                *(ushort4*)&dst[ctd * 16 + quad * 4] = o;
            }
        }
    }
}

// ---------------------------------------------------------------------------
extern "C" void kernel_launch(void* const* d_in, const int* in_sizes, int n_in,
                              void* d_out, int out_size, void* d_ws, size_t ws_size,
                              hipStream_t stream) {
    const float* X     = (const float*)d_in[0];
    const float* qkv_w = (const float*)d_in[1];
    const float* qkv_b = (const float*)d_in[2];
    const float* o_w   = (const float*)d_in[3];
    const float* o_b   = (const float*)d_in[4];
    float* out = (float*)d_out;

    const size_t BTC = (size_t)Bn * Tn * Cn;     // 8388608
    ushort* Xb  = (ushort*)d_ws;                 // bf16 [8192,1024]
    ushort* Wqt = Xb  + BTC;                     // bf16 [3072,1024]
    ushort* Wot = Wqt + 3 * Cn * Cn;             // bf16 [1024,1024]
    ushort* Qb  = Wot + Cn * Cn;                 // bf16 [B,H,T,D]
    ushort* Kb  = Qb  + BTC;
    ushort* Vtb = Kb  + BTC;                     // bf16 [B,H,D,T]
    ushort* Ao  = Vtb + BTC;                     // bf16 [B*T,C]

    cvt_bf16<<<dim3((int)(BTC / 8 / 256)), 256, 0, stream>>>(X, Xb, (int)BTC);
    transpose_bf16<<<dim3(3 * Cn / 32, Kdim / 32), 256, 0, stream>>>(qkv_w, Wqt, 3 * Cn);
    transpose_bf16<<<dim3(Cn / 32, Kdim / 32), 256, 0, stream>>>(o_w, Wot, Cn);

    gemm_bt<1><<<dim3(3 * Cn / 128, 8192 / 128), 256, 0, stream>>>(
        Xb, Wqt, qkv_b, nullptr, Qb, Kb, Vtb);
    attn_mfma<<<dim3(8, Bn * Hn), 256, 0, stream>>>(Qb, Kb, Vtb, Ao);
    gemm_bt<0><<<dim3(Cn / 128, 8192 / 128), 256, 0, stream>>>(
        Ao, Wot, o_b, out, nullptr, nullptr, nullptr);
}

// Round 5
// 313.428 us; speedup vs baseline: 10.3501x; 1.1471x over previous
//
#include <hip/hip_runtime.h>
#include <hip/hip_bf16.h>

// Problem constants
#define Bn 4
#define Tn 2048
#define Cn 1024
#define Hn 16
#define Dn 64
#define Kdim 1024

typedef __bf16 bf16x8 __attribute__((ext_vector_type(8)));
typedef float f32x4 __attribute__((ext_vector_type(4)));
union B8 { uint4 u; bf16x8 f; ushort s[8]; };

static __device__ __forceinline__ ushort f2bf(float x) {
    __hip_bfloat16 h = __float2bfloat16(x);
    return *(ushort*)&h;
}

#define AS1 __attribute__((address_space(1)))
#define AS3 __attribute__((address_space(3)))

static __device__ __forceinline__ void gload_lds16(const ushort* g, ushort* l) {
    __builtin_amdgcn_global_load_lds((AS1 const uint4*)(const void*)g,
                                     (AS3 uint4*)(void*)l, 16, 0, 0);
}

// ---------------------------------------------------------------------------
// fp32 -> bf16 cast (layout preserved). n multiple of 8.
// ---------------------------------------------------------------------------
__global__ __launch_bounds__(256) void cvt_bf16(
    const float* __restrict__ src, ushort* __restrict__ dst, int n)
{
    int i = (blockIdx.x * 256 + threadIdx.x) * 8;
    if (i >= n) return;
    float4 a = *(const float4*)&src[i];
    float4 b = *(const float4*)&src[i + 4];
    ushort4 o0, o1;
    o0.x = f2bf(a.x); o0.y = f2bf(a.y); o0.z = f2bf(a.z); o0.w = f2bf(a.w);
    o1.x = f2bf(b.x); o1.y = f2bf(b.y); o1.z = f2bf(b.z); o1.w = f2bf(b.w);
    *(ushort4*)&dst[i] = o0;
    *(ushort4*)&dst[i + 4] = o1;
}

// ---------------------------------------------------------------------------
// W[K,N] fp32 -> Wt[N,K] bf16 (32x32 LDS tile transpose)
// ---------------------------------------------------------------------------
__global__ __launch_bounds__(256) void transpose_bf16(
    const float* __restrict__ W, ushort* __restrict__ Wt, int N)
{
    __shared__ float Ls[32][33];
    const int k0 = blockIdx.y * 32, n0 = blockIdx.x * 32;
    const int tx = threadIdx.x & 31, ty = threadIdx.x >> 5;
    #pragma unroll
    for (int i = 0; i < 4; i++) {
        int r = ty + i * 8;
        Ls[r][tx] = W[(size_t)(k0 + r) * N + n0 + tx];
    }
    __syncthreads();
    #pragma unroll
    for (int i = 0; i < 4; i++) {
        int r = ty + i * 8;
        Wt[(size_t)(n0 + r) * Kdim + k0 + tx] = f2bf(Ls[tx][r]);
    }
}

// ---------------------------------------------------------------------------
// bf16 MFMA GEMM (m97 structure): C[M,N] = A[M,K] @ Bt[N,K]^T (+bias).
// EPI 0: fp32 out + bias.  EPI 1: bf16 Q[B,H,T,D] (pre-scaled by
// D^-0.5*log2(e) for exp2-domain softmax), K[B,H,T,D], V^T [B,H,D,T].
// ---------------------------------------------------------------------------
template <int EPI>
__global__ __launch_bounds__(256) void gemm_bt(
    const ushort* __restrict__ A, const ushort* __restrict__ Bt,
    const float* __restrict__ bias,
    float* __restrict__ Out, ushort* __restrict__ Qb,
    ushort* __restrict__ Kb, ushort* __restrict__ Vtb)
{
    const int m0 = blockIdx.y * 128;
    const int n0 = blockIdx.x * 128;
    const int t  = threadIdx.x;
    const int wave = t >> 6, lane = t & 63;
    const int ln = lane & 15, quad = lane >> 4;
    const int wm = wave >> 1, wn = wave & 1;

    __shared__ ushort As[128 * 64];
    __shared__ ushort Bs[128 * 64];

    f32x4 acc[4][4] = {};

    for (int k0 = 0; k0 < Kdim; k0 += 64) {
        __syncthreads();
        #pragma unroll
        for (int it = 0; it < 4; it++) {
            int c = it * 256 + wave * 64 + lane;
            int row = c >> 3, seg = c & 7;
            int gseg = seg ^ (row & 7);
            gload_lds16(&A [(size_t)(m0 + row) * Kdim + k0 + gseg * 8], &As[c * 8]);
            gload_lds16(&Bt[(size_t)(n0 + row) * Kdim + k0 + gseg * 8], &Bs[c * 8]);
        }
        __syncthreads();

        #pragma unroll
        for (int ks = 0; ks < 2; ks++) {
            bf16x8 af[4], bf[4];
            #pragma unroll
            for (int mm = 0; mm < 4; mm++) {
                int row = wm * 64 + mm * 16 + ln;
                int seg = (ks * 4 + quad) ^ (ln & 7);
                B8 tmp; tmp.u = *(const uint4*)&As[row * 64 + seg * 8];
                af[mm] = tmp.f;
            }
            #pragma unroll
            for (int nn = 0; nn < 4; nn++) {
                int row = wn * 64 + nn * 16 + ln;
                int seg = (ks * 4 + quad) ^ (ln & 7);
                B8 tmp; tmp.u = *(const uint4*)&Bs[row * 64 + seg * 8];
                bf[nn] = tmp.f;
            }
            #pragma unroll
            for (int mm = 0; mm < 4; mm++)
                #pragma unroll
                for (int nn = 0; nn < 4; nn++)
                    acc[mm][nn] = __builtin_amdgcn_mfma_f32_16x16x32_bf16(
                        af[mm], bf[nn], acc[mm][nn], 0, 0, 0);
        }
    }

    if (EPI == 0) {
        #pragma unroll
        for (int nn = 0; nn < 4; nn++) {
            int n = n0 + wn * 64 + nn * 16 + ln;
            float bv = bias[n];
            #pragma unroll
            for (int mm = 0; mm < 4; mm++) {
                int mbase = m0 + wm * 64 + mm * 16 + quad * 4;
                #pragma unroll
                for (int reg = 0; reg < 4; reg++)
                    Out[(size_t)(mbase + reg) * 1024 + n] = acc[mm][nn][reg] + bv;
            }
        }
    } else {
        const int nb = n0 + wn * 64;
        const int which = nb >> 10;            // 0=Q 1=K 2=V
        const int h = (nb & 1023) >> 6;
        // Q: fold D^-0.5 and log2(e) (exp2-domain softmax) into the scale
        const float scale = (which == 0) ? 0.125f * 1.44269504088896f : 1.0f;
        #pragma unroll
        for (int nn = 0; nn < 4; nn++) {
            int n = nb + nn * 16 + ln;
            float bv = bias[n];
            #pragma unroll
            for (int mm = 0; mm < 4; mm++) {
                int mbase = m0 + wm * 64 + mm * 16 + quad * 4;
                int b_ = mbase >> 11, tt = mbase & 2047;
                if (which == 2) {
                    ushort4 o;
                    #pragma unroll
                    for (int reg = 0; reg < 4; reg++)
                        ((ushort*)&o)[reg] = f2bf(acc[mm][nn][reg] + bv);
                    *(ushort4*)&Vtb[((size_t)((b_ * Hn + h) * Dn) + nn * 16 + ln) * Tn + tt] = o;
                } else {
                    ushort* dst = (which == 0) ? Qb : Kb;
                    #pragma unroll
                    for (int reg = 0; reg < 4; reg++)
                        dst[((size_t)((b_ * Hn + h) * Tn + tt + reg)) * Dn + nn * 16 + ln] =
                            f2bf((acc[mm][nn][reg] + bv) * scale);
                }
            }
        }
    }
}

// ---------------------------------------------------------------------------
// Flash attention v3: pipelined. Block = 128 Q rows (4 waves x 32q),
// K-chunk 128. K double-buffered in LDS (prefetch next chunk right after the
// loop-top barrier -> its latency hides under this chunk's compute). V^T
// fragments load DIRECTLY global->VGPR (A-layout is natural in [B,H,D,T]),
// issued at chunk start, consumed ~600cy later at PV. P is wave-private LDS.
// Exactly one barrier per chunk. exp2-domain softmax.
// ---------------------------------------------------------------------------
__global__ __launch_bounds__(256, 2) void attn_mfma(
    const ushort* __restrict__ Qb, const ushort* __restrict__ Kb,
    const ushort* __restrict__ Vtb, ushort* __restrict__ Ob)
{
    const int pair = blockIdx.x;   // 0..7
    const int bh   = blockIdx.y;   // 0..63
    const int t    = threadIdx.x;
    const int wave = t >> 6, lane = t & 63;
    const int ln   = lane & 15, quad = lane >> 4;

    __shared__ ushort Ks[2][128 * 64];  // [key][d], xor-swizzled segs, 2x16KB
    __shared__ ushort Ps[4][32 * 66];   // per-wave P half [q][key(64)+pad]

    const ushort* KgB = Kb  + (size_t)bh * Tn * Dn;
    const ushort* VgB = Vtb + (size_t)bh * Dn * Tn;
    const int b_ = bh >> 4, h = bh & 15;

    // stage K chunk `kc` into buffer `buf` (4 global_load_lds per wave)
    #define STAGE_K(kc, buf)                                                   \
        do {                                                                   \
            _Pragma("unroll")                                                  \
            for (int it = 0; it < 4; it++) {                                   \
                int c = it * 256 + wave * 64 + lane;                           \
                int row = c >> 3, seg = c & 7;                                 \
                int gs = seg ^ (row & 7);                                      \
                gload_lds16(&KgB[(size_t)((kc) * 128 + row) * Dn + gs * 8],    \
                            &Ks[buf][c * 8]);                                  \
            }                                                                  \
        } while (0)

    int cur = 0;
    STAGE_K(0, 0);

    for (int tile = 0; tile < 2; tile++) {
        const int qt = (tile == 0) ? pair : 15 - pair;
        const int q0 = qt * 128;

        // Q B-fragments: B[k=d][n=q], lane ln = q, d = ks*32+quad*8+j
        const ushort* Qg = Qb + ((size_t)bh * Tn + q0 + wave * 32) * Dn;
        bf16x8 qf[2][2];
        #pragma unroll
        for (int ns = 0; ns < 2; ns++)
            #pragma unroll
            for (int ks = 0; ks < 2; ks++) {
                B8 tmp; tmp.u = *(const uint4*)&Qg[(ns * 16 + ln) * 64 + ks * 32 + quad * 8];
                qf[ns][ks] = tmp.f;
            }

        f32x4 Oacc[4][2] = {};   // O^T [d-subtile][ns], lane ln = q
        float m_r[2] = {-1e30f, -1e30f}, l_r[2] = {0.f, 0.f};

        for (int kc = 0; kc <= qt; kc++) {
            __syncthreads();   // publishes K(kc); drains prefetch issued last iter

            // V^T fragments for this chunk: direct global->VGPR, A-layout.
            // Issued FIRST so PV's waitcnt doesn't cover the K prefetch.
            B8 vfr[4][4];      // [d-subtile][32-key step]
            #pragma unroll
            for (int gks = 0; gks < 4; gks++)
                #pragma unroll
                for (int ctd = 0; ctd < 4; ctd++)
                    vfr[ctd][gks].u = *(const uint4*)&VgB[
                        (size_t)(ctd * 16 + ln) * Tn + kc * 128 + gks * 32 + quad * 8];

            // prefetch next K chunk into the other buffer
            if (kc < qt)            STAGE_K(kc + 1, cur ^ 1);
            else if (tile == 0)     STAGE_K(0, cur ^ 1);   // tile-1 prologue

            // S^T = K Q^T: rows = keys (128 = 8 ct), cols = q (32 = 2 ns)
            const ushort* Kc = Ks[cur];
            f32x4 S[8][2] = {};
            #pragma unroll
            for (int ks = 0; ks < 2; ks++)
                #pragma unroll
                for (int ct = 0; ct < 8; ct++) {
                    B8 a; a.u = *(const uint4*)&Kc[(ct * 16 + ln) * 64 +
                                                   (((ks * 4 + quad) ^ (ln & 7)) * 8)];
                    #pragma unroll
                    for (int ns = 0; ns < 2; ns++)
                        S[ct][ns] = __builtin_amdgcn_mfma_f32_16x16x32_bf16(
                            a.f, qf[ns][ks], S[ct][ns], 0, 0, 0);
                }

            if (kc == qt) {   // causal mask on diagonal chunk
                #pragma unroll
                for (int ct = 0; ct < 8; ct++) {
                    int keyl = ct * 16 + quad * 4;
                    #pragma unroll
                    for (int ns = 0; ns < 2; ns++) {
                        int ql = wave * 32 + ns * 16 + ln;
                        #pragma unroll
                        for (int reg = 0; reg < 4; reg++)
                            if (keyl + reg > ql) S[ct][ns][reg] = -1e30f;
                    }
                }
            }

            // per-lane online softmax stats (q = ln; reduce over quads)
            float alpha[2], ssum[2] = {0.f, 0.f};
            #pragma unroll
            for (int ns = 0; ns < 2; ns++) {
                float pm = -1e30f;
                #pragma unroll
                for (int ct = 0; ct < 8; ct++)
                    #pragma unroll
                    for (int reg = 0; reg < 4; reg++)
                        pm = fmaxf(pm, S[ct][ns][reg]);
                pm = fmaxf(pm, __shfl_xor(pm, 16));
                pm = fmaxf(pm, __shfl_xor(pm, 32));
                float mn = fmaxf(m_r[ns], pm);
                alpha[ns] = exp2f(m_r[ns] - mn);
                m_r[ns] = mn;
                #pragma unroll
                for (int ctd = 0; ctd < 4; ctd++)
                    Oacc[ctd][ns] *= alpha[ns];
            }

            ushort* Pw = Ps[wave];
            #pragma unroll
            for (int pass = 0; pass < 2; pass++) {
                // exp2 + write P half (keys pass*64 .. +63), b64 stores
                #pragma unroll
                for (int ct_h = 0; ct_h < 4; ct_h++) {
                    int ct = pass * 4 + ct_h;
                    #pragma unroll
                    for (int ns = 0; ns < 2; ns++) {
                        ushort4 o;
                        #pragma unroll
                        for (int reg = 0; reg < 4; reg++) {
                            float p = exp2f(S[ct][ns][reg] - m_r[ns]);
                            ssum[ns] += p;
                            ((ushort*)&o)[reg] = f2bf(p);
                        }
                        *(ushort4*)&Pw[(ns * 16 + ln) * 66 + ct_h * 16 + quad * 4] = o;
                    }
                }
                // O^T += V^T P^T over this half's 64 keys (V from registers)
                #pragma unroll
                for (int kh = 0; kh < 2; kh++) {
                    int gks = pass * 2 + kh;       // global 32-key step
                    #pragma unroll
                    for (int ns = 0; ns < 2; ns++) {
                        B8 pfr; pfr.u = *(const uint4*)&Pw[(ns * 16 + ln) * 66 +
                                                           kh * 32 + quad * 8];
                        #pragma unroll
                        for (int ctd = 0; ctd < 4; ctd++)
                            Oacc[ctd][ns] = __builtin_amdgcn_mfma_f32_16x16x32_bf16(
                                vfr[ctd][gks].f, pfr.f, Oacc[ctd][ns], 0, 0, 0);
                    }
                }
            }
            #pragma unroll
            for (int ns = 0; ns < 2; ns++) {
                float s = ssum[ns];
                s += __shfl_xor(s, 16);
                s += __shfl_xor(s, 32);
                l_r[ns] = l_r[ns] * alpha[ns] + s;
            }
            cur ^= 1;
        }

        // epilogue: bf16 attn_out [B*T][C]; lane ln = token, regs = d
        #pragma unroll
        for (int ns = 0; ns < 2; ns++) {
            float inv = 1.0f / l_r[ns];
            int token = q0 + wave * 32 + ns * 16 + ln;
            ushort* dst = Ob + ((size_t)(b_ * Tn + token)) * Cn + h * 64;
            #pragma unroll
            for (int ctd = 0; ctd < 4; ctd++) {
                ushort4 o;
                #pragma unroll
                for (int reg = 0; reg < 4; reg++)
                    ((ushort*)&o)[reg] = f2bf(Oacc[ctd][ns][reg] * inv);
                *(ushort4*)&dst[ctd * 16 + quad * 4] = o;
            }
        }
    }
    #undef STAGE_K
}

// ---------------------------------------------------------------------------
extern "C" void kernel_launch(void* const* d_in, const int* in_sizes, int n_in,
                              void* d_out, int out_size, void* d_ws, size_t ws_size,
                              hipStream_t stream) {
    const float* X     = (const float*)d_in[0];
    const float* qkv_w = (const float*)d_in[1];
    const float* qkv_b = (const float*)d_in[2];
    const float* o_w   = (const float*)d_in[3];
    const float* o_b   = (const float*)d_in[4];
    float* out = (float*)d_out;

    const size_t BTC = (size_t)Bn * Tn * Cn;     // 8388608
    ushort* Xb  = (ushort*)d_ws;                 // bf16 [8192,1024]
    ushort* Wqt = Xb  + BTC;                     // bf16 [3072,1024]
    ushort* Wot = Wqt + 3 * Cn * Cn;             // bf16 [1024,1024]
    ushort* Qb  = Wot + Cn * Cn;                 // bf16 [B,H,T,D]
    ushort* Kb  = Qb  + BTC;
    ushort* Vtb = Kb  + BTC;                     // bf16 [B,H,D,T]
    ushort* Ao  = Vtb + BTC;                     // bf16 [B*T,C]

    cvt_bf16<<<dim3((int)(BTC / 8 / 256)), 256, 0, stream>>>(X, Xb, (int)BTC);
    transpose_bf16<<<dim3(3 * Cn / 32, Kdim / 32), 256, 0, stream>>>(qkv_w, Wqt, 3 * Cn);
    transpose_bf16<<<dim3(Cn / 32, Kdim / 32), 256, 0, stream>>>(o_w, Wot, Cn);

    gemm_bt<1><<<dim3(3 * Cn / 128, 8192 / 128), 256, 0, stream>>>(
        Xb, Wqt, qkv_b, nullptr, Qb, Kb, Vtb);
    attn_mfma<<<dim3(8, Bn * Hn), 256, 0, stream>>>(Qb, Kb, Vtb, Ao);
    gemm_bt<0><<<dim3(Cn / 128, 8192 / 128), 256, 0, stream>>>(
        Ao, Wot, o_b, out, nullptr, nullptr, nullptr);
}